// Round 2
// baseline (12020.234 us; speedup 1.0000x reference)
//
#include <hip/hip_runtime.h>
#include <stdint.h>

// Problem constants
#define B_  4
#define S_  4096
#define D_  1024
#define N_  128
#define H_  512
#define BS_ (B_ * S_)       // 16384
#define R3_ (3 * H_)        // 1536

typedef unsigned int u32;
typedef short bf16x8 __attribute__((ext_vector_type(8)));
typedef float f32x4  __attribute__((ext_vector_type(4)));

// d_out layout: layer_out [BS_*D_] | final_ssm_state [B_*N_] | h_last [B_*H_]
#define FSS_OFF ((size_t)BS_ * D_)          // 16777216
#define HL_OFF  (FSS_OFF + (size_t)B_ * N_) // 16777728

// Workspace layout (bytes). U overlays xn+Ball (dead by the time U is written).
#define OFF_XN     ((size_t)0)
#define OFF_BALL   ((size_t)33554432)
#define OFF_U      ((size_t)0)
#define OFF_STATES ((size_t)50331648)
#define OFF_CFC    ((size_t)54525952)
#define OFF_BW     ((size_t)71303168)
#define OFF_CWT    ((size_t)71565312)
#define OFF_WXS    ((size_t)71827456)
#define OFF_WHS    ((size_t)74973184)
#define OFF_OW     ((size_t)76546048)
#define OFF_G      ((size_t)77594624)
#define OFF_UB     ((size_t)77987840)
#define OFF_HBUF   ((size_t)77993984)   // 2 slots * 4 * 512 u32 = 16 KiB

__device__ __forceinline__ unsigned short f2bf(float f) {
  u32 u = __float_as_uint(f);
  u32 r = (u + 0x7FFFu + ((u >> 16) & 1u)) >> 16;
  return (unsigned short)r;
}
__device__ __forceinline__ float bf2f(unsigned short h) {
  return __uint_as_float(((u32)h) << 16);
}

// ---------------- weight prep ----------------
__global__ void k_conv(const float* __restrict__ src, unsigned short* __restrict__ dst, int n) {
  int i = blockIdx.x * 256 + threadIdx.x;
  if (i < n) dst[i] = f2bf(src[i]);
}

__global__ void k_transpose_cw(const float* __restrict__ Cw, unsigned short* __restrict__ CwT) {
  int i = blockIdx.x * 256 + threadIdx.x;   // over N_*D_
  if (i < N_ * D_) {
    int n = i >> 10, d = i & 1023;
    CwT[i] = f2bf(Cw[d * N_ + n]);
  }
}

__global__ void k_build_wxs(const float* __restrict__ f1, const float* __restrict__ f2,
                            const float* __restrict__ ta, const float* __restrict__ tb,
                            unsigned short* __restrict__ Wxs) {
  int i = blockIdx.x * 256 + threadIdx.x;   // over R3_*D_
  if (i >= R3_ * D_) return;
  int r = i >> 10, d = i & 1023;
  int m = r >> 9, j = r & 511;
  int idx = j * (D_ + H_) + d;
  float v = (m == 0) ? f1[idx] : (m == 1) ? f2[idx] : (0.1f * ta[idx] + tb[idx]);
  Wxs[i] = f2bf(v);
}

// h-part weights, pre-scaled by 2^-23 (h is transported as 24-bit fixed point ints)
__global__ void k_build_whs(const float* __restrict__ f1, const float* __restrict__ f2,
                            const float* __restrict__ ta, const float* __restrict__ tb,
                            unsigned short* __restrict__ Whs) {
  int i = blockIdx.x * 256 + threadIdx.x;   // over R3_*H_
  if (i >= R3_ * H_) return;
  int r = i >> 9, k = i & 511;
  int m = r >> 9, j = r & 511;
  int idx = j * (D_ + H_) + D_ + k;
  float v = (m == 0) ? f1[idx] : (m == 1) ? f2[idx] : (0.1f * ta[idx] + tb[idx]);
  Whs[i] = f2bf(v * (1.0f / 8388608.0f));
}

// ub[r] = sum_d Wx[r][d]*C_b[d] + bias_r   (folds C_b through the x-part)
__global__ void k_build_ub(const float* __restrict__ f1w, const float* __restrict__ f2w,
                           const float* __restrict__ taw, const float* __restrict__ tbw,
                           const float* __restrict__ f1b, const float* __restrict__ f2b,
                           const float* __restrict__ tab, const float* __restrict__ tbb,
                           const float* __restrict__ Cb, float* __restrict__ ub) {
  int r = blockIdx.x * 256 + threadIdx.x;
  if (r >= R3_) return;
  int m = r >> 9, j = r & 511;
  float s = (m == 0) ? f1b[j] : (m == 1) ? f2b[j] : (0.1f * tab[j] + tbb[j]);
  for (int d = 0; d < D_; d++) {
    int idx = j * (D_ + H_) + d;
    float w = (m == 0) ? f1w[idx] : (m == 1) ? f2w[idx] : (0.1f * taw[idx] + tbw[idx]);
    s += w * Cb[d];
  }
  ub[r] = s;
}

// ---------------- LayerNorm -> bf16 ----------------
__global__ __launch_bounds__(256) void k_ln(const float* __restrict__ x,
                                            const float* __restrict__ g,
                                            const float* __restrict__ bta,
                                            unsigned short* __restrict__ xn) {
  int row = blockIdx.x;
  int tid = threadIdx.x;
  const float* xr = x + (size_t)row * D_;
  float4 v = ((const float4*)xr)[tid];
  float s = v.x + v.y + v.z + v.w;
  float q = v.x * v.x + v.y * v.y + v.z * v.z + v.w * v.w;
  for (int off = 32; off >= 1; off >>= 1) {
    s += __shfl_xor(s, off, 64);
    q += __shfl_xor(q, off, 64);
  }
  __shared__ float red[8];
  int wid = tid >> 6, lane = tid & 63;
  if (lane == 0) { red[wid] = s; red[4 + wid] = q; }
  __syncthreads();
  s = red[0] + red[1] + red[2] + red[3];
  q = red[4] + red[5] + red[6] + red[7];
  float mu = s * (1.0f / D_);
  float var = q * (1.0f / D_) - mu * mu;
  float rs = rsqrtf(var + 1e-5f);
  float4 gg = ((const float4*)g)[tid];
  float4 bb = ((const float4*)bta)[tid];
  ushort4 o;
  o.x = f2bf((v.x - mu) * rs * gg.x + bb.x);
  o.y = f2bf((v.y - mu) * rs * gg.y + bb.y);
  o.z = f2bf((v.z - mu) * rs * gg.z + bb.z);
  o.w = f2bf((v.w - mu) * rs * gg.w + bb.w);
  ((ushort4*)(xn + (size_t)row * D_))[tid] = o;
}

// ---------------- generic bf16 MFMA GEMM ----------------
// C[m][n] = sum_k A[m][k]*B[n][k] (+bias[n]) (+resid[m][n]); out fp32 (Cf) or bf16 (Cb).
// M,N multiples of 128; K multiple of 32.
__global__ __launch_bounds__(256) void k_gemm(const unsigned short* __restrict__ A,
                                              const unsigned short* __restrict__ Bm,
                                              const float* __restrict__ bias,
                                              const float* __restrict__ resid,
                                              float* __restrict__ Cf,
                                              unsigned short* __restrict__ Cb,
                                              int M, int N, int K) {
  int nt = N >> 7;
  int bx = blockIdx.x % nt, by = blockIdx.x / nt;
  int m0 = by << 7, n0 = bx << 7;
  int tid = threadIdx.x;
  __shared__ unsigned short Al[4][128][8];   // [k8][row][8]
  __shared__ unsigned short Bl[4][128][8];
  int lane = tid & 63, wid = tid >> 6;
  int wr = (wid >> 1) << 6, wc = (wid & 1) << 6;
  f32x4 acc[4][4];
#pragma unroll
  for (int i = 0; i < 4; i++)
#pragma unroll
    for (int j = 0; j < 4; j++) acc[i][j] = (f32x4){0.f, 0.f, 0.f, 0.f};

  int ur0 = tid >> 2, uk = tid & 3;
  int ur1 = ur0 + 64;
  int kt_n = K >> 5;
  for (int kt = 0; kt < kt_n; kt++) {
    int kb = (kt << 5) + (uk << 3);
    uint4 a0 = *(const uint4*)(A + (size_t)(m0 + ur0) * K + kb);
    uint4 a1 = *(const uint4*)(A + (size_t)(m0 + ur1) * K + kb);
    uint4 b0 = *(const uint4*)(Bm + (size_t)(n0 + ur0) * K + kb);
    uint4 b1 = *(const uint4*)(Bm + (size_t)(n0 + ur1) * K + kb);
    *(uint4*)&Al[uk][ur0][0] = a0;
    *(uint4*)&Al[uk][ur1][0] = a1;
    *(uint4*)&Bl[uk][ur0][0] = b0;
    *(uint4*)&Bl[uk][ur1][0] = b1;
    __syncthreads();
    int g = lane >> 4, r = lane & 15;
    bf16x8 af[4], bfv[4];
#pragma unroll
    for (int mf = 0; mf < 4; mf++) af[mf] = *(const bf16x8*)&Al[g][wr + mf * 16 + r][0];
#pragma unroll
    for (int nf = 0; nf < 4; nf++) bfv[nf] = *(const bf16x8*)&Bl[g][wc + nf * 16 + r][0];
#pragma unroll
    for (int mf = 0; mf < 4; mf++)
#pragma unroll
      for (int nf = 0; nf < 4; nf++)
        acc[mf][nf] = __builtin_amdgcn_mfma_f32_16x16x32_bf16(af[mf], bfv[nf], acc[mf][nf], 0, 0, 0);
    __syncthreads();
  }
  int r4 = (lane >> 4) << 2;
  int cl = lane & 15;
#pragma unroll
  for (int mf = 0; mf < 4; mf++) {
#pragma unroll
    for (int nf = 0; nf < 4; nf++) {
#pragma unroll
      for (int e = 0; e < 4; e++) {
        int row = m0 + wr + mf * 16 + r4 + e;
        int col = n0 + wc + nf * 16 + cl;
        float v = acc[mf][nf][e];
        if (bias)  v += bias[col];
        size_t idx = (size_t)row * N + col;
        if (resid) v += resid[idx];
        if (Cb) Cb[idx] = f2bf(v); else Cf[idx] = v;
      }
    }
  }
}

// ---------------- SSM prefix scan ----------------
// states[b,s,n] = A^s * sum_{t<=s} Ball[b,t,n]/max(A^t,1e-8);  A = sigmoid(A_log)
__global__ __launch_bounds__(1024) void k_ssm(const float* __restrict__ Ball,
                                              const float* __restrict__ A_log,
                                              unsigned short* __restrict__ states,
                                              float* __restrict__ fss) {
  int b = blockIdx.x >> 1, half = blockIdx.x & 1;
  int tid = threadIdx.x;
  int nloc = tid & 63, chunk = tid >> 6;         // 16 chunks of 256 steps
  int n = half * 64 + nloc;
  float A = 1.0f / (1.0f + expf(-A_log[n]));
  float l2A = log2f(A);
  __shared__ float sums[16][64];
  float acc = 0.f;
  int sbase = chunk << 8;
  for (int i = 0; i < 256; i++) {
    int s = sbase + i;
    float ap = exp2f((float)s * l2A);
    acc += Ball[((size_t)b * S_ + s) * N_ + n] / fmaxf(ap, 1e-8f);
  }
  sums[chunk][nloc] = acc;
  __syncthreads();
  float c = 0.f;
  for (int cc = 0; cc < 16; cc++)
    if (cc < chunk) c += sums[cc][nloc];
  for (int i = 0; i < 256; i++) {
    int s = sbase + i;
    float ap = exp2f((float)s * l2A);
    c += Ball[((size_t)b * S_ + s) * N_ + n] / fmaxf(ap, 1e-8f);
    float st = ap * c;
    states[((size_t)b * S_ + s) * N_ + n] = f2bf(st);
    if (s == S_ - 1) fss[b * N_ + n] = st;
  }
}

// ---------------- CfC sequential scan ----------------
// 32 persistent blocks (8 per batch). Block (b,p) owns j in [64p, 64p+64).
// 16 lanes per j; lane l16 holds weight cols {32i+2*l16, 32i+2*l16+1 : i<16} of rows
// j (ff1), 512+j (ff2), 1024+j (t-fused), pre-scaled by 2^-23.
// h words: 24-bit fixed value | 8-bit step tag; 2 global slots (tag parity) -> provably
// no overwrite before universal consumption. Per step: 512 loader lanes poll their word
// into LDS, barrier, everyone dots from LDS, 16-lane xor-reduce, lane0 applies U + acts.
__global__ __launch_bounds__(1024) void k_cfc(const unsigned short* __restrict__ U,
                                              const unsigned short* __restrict__ Whs,
                                              unsigned short* __restrict__ cfc,
                                              float* __restrict__ dout,
                                              u32* __restrict__ hbuf) {
  int bid = blockIdx.x;
  int b = bid >> 3, p = bid & 7;
  int tid = threadIdx.x;
  int jl = tid >> 4, l16 = tid & 15;
  int j = p * 64 + jl;

  u32 w1[16], w2[16], w3[16];
  {
    const u32* Wr1 = (const u32*)Whs + (((size_t)j * H_) >> 1);
    const u32* Wr2 = (const u32*)Whs + (((size_t)(H_ + j) * H_) >> 1);
    const u32* Wr3 = (const u32*)Whs + (((size_t)(2 * H_ + j) * H_) >> 1);
#pragma unroll
    for (int i = 0; i < 16; i++) {
      w1[i] = Wr1[i * 16 + l16];
      w2[i] = Wr2[i * 16 + l16];
      w3[i] = Wr3[i * 16 + l16];
    }
  }

  __shared__ u32 lh[2][512];
  if (l16 == 0) {  // init h0 = 0, tag 0, slot 0
    __hip_atomic_store(&hbuf[(size_t)b * 512 + j], 0u, __ATOMIC_RELAXED, __HIP_MEMORY_SCOPE_AGENT);
  }

  float hn = 0.f;
  const unsigned short* Ub = U + (size_t)b * S_ * R3_;
  for (int s = 0; s < S_; s++) {
    float u1 = 0.f, u2 = 0.f, u3 = 0.f;
    if (l16 == 0) {
      const unsigned short* up = Ub + (size_t)s * R3_;
      u1 = bf2f(up[j]); u2 = bf2f(up[H_ + j]); u3 = bf2f(up[2 * H_ + j]);
    }
    if (tid < 512) {
      const u32* src = hbuf + (size_t)(s & 1) * 2048 + (size_t)b * 512 + tid;
      u32 w;
      int want = s & 0xFF;
      do {
        w = __hip_atomic_load(src, __ATOMIC_RELAXED, __HIP_MEMORY_SCOPE_AGENT);
      } while ((int)(w & 0xFFu) != want);
      lh[s & 1][tid] = w;
    }
    __syncthreads();

    float z1 = 0.f, z2 = 0.f, z3 = 0.f;
    const u32* lp = &lh[s & 1][0] + 2 * l16;
#pragma unroll
    for (int i = 0; i < 16; i++) {
      uint2 hw = *(const uint2*)(lp + 32 * i);
      float ha = (float)(((int)hw.x) >> 8);    // scale 2^-23 folded into weights
      float hb = (float)(((int)hw.y) >> 8);
      u32 q1 = w1[i], q2 = w2[i], q3 = w3[i];
      float w1a = __uint_as_float(q1 << 16), w1b = __uint_as_float(q1 & 0xFFFF0000u);
      float w2a = __uint_as_float(q2 << 16), w2b = __uint_as_float(q2 & 0xFFFF0000u);
      float w3a = __uint_as_float(q3 << 16), w3b = __uint_as_float(q3 & 0xFFFF0000u);
      z1 += ha * w1a + hb * w1b;
      z2 += ha * w2a + hb * w2b;
      z3 += ha * w3a + hb * w3b;
    }
    for (int m = 8; m >= 1; m >>= 1) {
      z1 += __shfl_xor(z1, m, 16);
      z2 += __shfl_xor(z2, m, 16);
      z3 += __shfl_xor(z3, m, 16);
    }
    if (l16 == 0) {
      z1 += u1; z2 += u2; z3 += u3;
      float e1 = __expf(2.f * z1); float a1 = 1.f - 2.f / (e1 + 1.f);
      float e2 = __expf(2.f * z2); float a2 = 1.f - 2.f / (e2 + 1.f);
      float ti = 1.f / (1.f + __expf(-z3));
      hn = a1 + ti * (a2 - a1);
      float hc = fminf(fmaxf(hn, -0.99999988f), 0.99999988f);
      int q = (int)rintf(hc * 8388608.f);
      u32 word = (((u32)q) << 8) | ((u32)((s + 1) & 0xFF));
      u32* dst = hbuf + (size_t)((s + 1) & 1) * 2048 + (size_t)b * 512 + j;
      __hip_atomic_store(dst, word, __ATOMIC_RELAXED, __HIP_MEMORY_SCOPE_AGENT);
      cfc[((size_t)b * S_ + s) * H_ + j] = f2bf(hn);
    }
  }
  if (l16 == 0) dout[HL_OFF + (size_t)b * H_ + j] = hn;
}

// ---------------- launch ----------------
extern "C" void kernel_launch(void* const* d_in, const int* in_sizes, int n_in,
                              void* d_out, int out_size, void* d_ws, size_t ws_size,
                              hipStream_t stream) {
  const float* x     = (const float*)d_in[0];
  const float* A_log = (const float*)d_in[1];
  const float* B_w   = (const float*)d_in[2];
  const float* B_b   = (const float*)d_in[3];
  const float* C_w   = (const float*)d_in[4];
  const float* C_b   = (const float*)d_in[5];
  const float* ng    = (const float*)d_in[6];
  const float* nbv   = (const float*)d_in[7];
  const float* f1w   = (const float*)d_in[8];
  const float* f1b   = (const float*)d_in[9];
  const float* f2w   = (const float*)d_in[10];
  const float* f2b   = (const float*)d_in[11];
  const float* taw   = (const float*)d_in[12];
  const float* tab   = (const float*)d_in[13];
  const float* tbw   = (const float*)d_in[14];
  const float* tbb   = (const float*)d_in[15];
  const float* ow    = (const float*)d_in[16];
  const float* ob    = (const float*)d_in[17];
  float* dout = (float*)d_out;
  char* ws = (char*)d_ws;

  unsigned short* xn_b     = (unsigned short*)(ws + OFF_XN);
  float*          Ball_f   = (float*)(ws + OFF_BALL);
  unsigned short* U_b      = (unsigned short*)(ws + OFF_U);
  unsigned short* states_b = (unsigned short*)(ws + OFF_STATES);
  unsigned short* cfc_b    = (unsigned short*)(ws + OFF_CFC);
  unsigned short* Bw_b     = (unsigned short*)(ws + OFF_BW);
  unsigned short* CwT_b    = (unsigned short*)(ws + OFF_CWT);
  unsigned short* Wxs_b    = (unsigned short*)(ws + OFF_WXS);
  unsigned short* Whs_b    = (unsigned short*)(ws + OFF_WHS);
  unsigned short* OW_b     = (unsigned short*)(ws + OFF_OW);
  unsigned short* G_b      = (unsigned short*)(ws + OFF_G);
  float*          ub_f     = (float*)(ws + OFF_UB);
  u32*            hbuf_u   = (u32*)(ws + OFF_HBUF);

  // weight prep
  k_conv<<<(N_ * D_ + 255) / 256, 256, 0, stream>>>(B_w, Bw_b, N_ * D_);
  k_transpose_cw<<<(N_ * D_ + 255) / 256, 256, 0, stream>>>(C_w, CwT_b);
  k_build_wxs<<<(R3_ * D_ + 255) / 256, 256, 0, stream>>>(f1w, f2w, taw, tbw, Wxs_b);
  k_build_whs<<<(R3_ * H_ + 255) / 256, 256, 0, stream>>>(f1w, f2w, taw, tbw, Whs_b);
  k_conv<<<(D_ * H_ + 255) / 256, 256, 0, stream>>>(ow, OW_b, D_ * H_);
  k_build_ub<<<(R3_ + 255) / 256, 256, 0, stream>>>(f1w, f2w, taw, tbw, f1b, f2b, tab, tbb, C_b, ub_f);

  // LN -> xn (bf16)
  k_ln<<<BS_, 256, 0, stream>>>(x, ng, nbv, xn_b);
  // Ball = xn @ B_w^T + B_b   (fp32)
  k_gemm<<<(BS_ / 128) * (N_ / 128), 256, 0, stream>>>(xn_b, Bw_b, B_b, nullptr, Ball_f, nullptr, BS_, N_, 1024);
  // states (bf16) + final_ssm_state -> d_out
  k_ssm<<<8, 1024, 0, stream>>>(Ball_f, A_log, states_b, dout + FSS_OFF);
  // G = Wxs @ C_w  (1536 x 128, bf16)
  k_gemm<<<(R3_ / 128) * (N_ / 128), 256, 0, stream>>>(Wxs_b, CwT_b, nullptr, nullptr, nullptr, G_b, R3_, N_, 1024);
  // U = states @ G^T + ub  (16384 x 1536, bf16)
  k_gemm<<<(BS_ / 128) * (R3_ / 128), 256, 0, stream>>>(states_b, G_b, ub_f, nullptr, nullptr, U_b, BS_, R3_, N_);
  // sequential CfC scan -> cfc (bf16), h_last -> d_out
  k_cfc<<<32, 1024, 0, stream>>>(U_b, Whs_b, cfc_b, dout, hbuf_u);
  // layer_out = x + cfc @ out_w^T + out_b  (fp32 -> d_out)
  k_gemm<<<(BS_ / 128) * (D_ / 128), 256, 0, stream>>>(cfc_b, OW_b, ob, x, dout, nullptr, BS_, D_, H_);

  (void)in_sizes; (void)n_in; (void)out_size; (void)ws_size;
}

// Round 4
// 10473.838 us; speedup vs baseline: 1.1476x; 1.1476x over previous
//
#include <hip/hip_runtime.h>
#include <hip/hip_fp16.h>
#include <stdint.h>

// Problem constants
#define B_  4
#define S_  4096
#define D_  1024
#define N_  128
#define H_  512
#define BS_ (B_ * S_)       // 16384
#define R3_ (3 * H_)        // 1536

typedef unsigned int u32;
typedef short bf16x8 __attribute__((ext_vector_type(8)));
typedef float f32x4  __attribute__((ext_vector_type(4)));
typedef _Float16 f16x2 __attribute__((ext_vector_type(2)));

// d_out layout: layer_out [BS_*D_] | final_ssm_state [B_*N_] | h_last [B_*H_]
#define FSS_OFF ((size_t)BS_ * D_)          // 16777216
#define HL_OFF  (FSS_OFF + (size_t)B_ * N_) // 16777728

// Workspace layout (bytes). U overlays xn+Ball (dead by the time U is written).
#define OFF_XN     ((size_t)0)
#define OFF_BALL   ((size_t)33554432)
#define OFF_U      ((size_t)0)
#define OFF_STATES ((size_t)50331648)
#define OFF_CFC    ((size_t)54525952)
#define OFF_BW     ((size_t)71303168)
#define OFF_CWT    ((size_t)71565312)
#define OFF_WXS    ((size_t)71827456)
#define OFF_WHP    ((size_t)74973184)   // f16-pair weights [1536][256] u32 = 1.5 MB
#define OFF_OW     ((size_t)76546048)
#define OFF_G      ((size_t)77594624)
#define OFF_UB     ((size_t)77987840)
#define OFF_HBUF   ((size_t)77993984)   // 2 slots * 4 * 512 u32 = 16 KiB

__device__ __forceinline__ unsigned short f2bf(float f) {
  u32 u = __float_as_uint(f);
  u32 r = (u + 0x7FFFu + ((u >> 16) & 1u)) >> 16;
  return (unsigned short)r;
}
__device__ __forceinline__ float bf2f(unsigned short h) {
  return __uint_as_float(((u32)h) << 16);
}

// dot2: f16x2 * f16x2 + f32, with fallback if the builtin is unavailable
__device__ __forceinline__ float dot2f(u32 wa, u32 hb, float acc) {
#if __has_builtin(__builtin_amdgcn_fdot2)
  return __builtin_amdgcn_fdot2(__builtin_bit_cast(f16x2, wa),
                                __builtin_bit_cast(f16x2, hb), acc, false);
#else
  f16x2 a = __builtin_bit_cast(f16x2, wa);
  f16x2 b = __builtin_bit_cast(f16x2, hb);
  return acc + (float)a[0] * (float)b[0] + (float)a[1] * (float)b[1];
#endif
}

// ---------------- weight prep ----------------
__global__ void k_conv(const float* __restrict__ src, unsigned short* __restrict__ dst, int n) {
  int i = blockIdx.x * 256 + threadIdx.x;
  if (i < n) dst[i] = f2bf(src[i]);
}

__global__ void k_transpose_cw(const float* __restrict__ Cw, unsigned short* __restrict__ CwT) {
  int i = blockIdx.x * 256 + threadIdx.x;   // over N_*D_
  if (i < N_ * D_) {
    int n = i >> 10, d = i & 1023;
    CwT[i] = f2bf(Cw[d * N_ + n]);
  }
}

__global__ void k_build_wxs(const float* __restrict__ f1, const float* __restrict__ f2,
                            const float* __restrict__ ta, const float* __restrict__ tb,
                            unsigned short* __restrict__ Wxs) {
  int i = blockIdx.x * 256 + threadIdx.x;   // over R3_*D_
  if (i >= R3_ * D_) return;
  int r = i >> 10, d = i & 1023;
  int m = r >> 9, j = r & 511;
  int idx = j * (D_ + H_) + d;
  float v = (m == 0) ? f1[idx] : (m == 1) ? f2[idx] : (0.1f * ta[idx] + tb[idx]);
  Wxs[i] = f2bf(v);
}

// h-part weights as f16 PAIRS: Whp[row][pi] = f16(W[row][2pi]) | f16(W[row][2pi+1])<<16
__global__ void k_build_whp(const float* __restrict__ f1, const float* __restrict__ f2,
                            const float* __restrict__ ta, const float* __restrict__ tb,
                            u32* __restrict__ Whp) {
  int i = blockIdx.x * 256 + threadIdx.x;   // over R3_*256
  if (i >= R3_ * 256) return;
  int r = i >> 8, pi = i & 255;
  int m = r >> 9, j = r & 511;
  int idx0 = j * (D_ + H_) + D_ + 2 * pi;
  float v0 = (m == 0) ? f1[idx0] : (m == 1) ? f2[idx0] : (0.1f * ta[idx0] + tb[idx0]);
  float v1 = (m == 0) ? f1[idx0+1] : (m == 1) ? f2[idx0+1] : (0.1f * ta[idx0+1] + tb[idx0+1]);
  u32 lo = __half_as_ushort(__float2half(v0));
  u32 hi = __half_as_ushort(__float2half(v1));
  Whp[i] = lo | (hi << 16);
}

// ub[r] = sum_d Wx[r][d]*C_b[d] + bias_r   (folds C_b through the x-part)
__global__ void k_build_ub(const float* __restrict__ f1w, const float* __restrict__ f2w,
                           const float* __restrict__ taw, const float* __restrict__ tbw,
                           const float* __restrict__ f1b, const float* __restrict__ f2b,
                           const float* __restrict__ tab, const float* __restrict__ tbb,
                           const float* __restrict__ Cb, float* __restrict__ ub) {
  int r = blockIdx.x * 256 + threadIdx.x;
  if (r >= R3_) return;
  int m = r >> 9, j = r & 511;
  float s = (m == 0) ? f1b[j] : (m == 1) ? f2b[j] : (0.1f * tab[j] + tbb[j]);
  for (int d = 0; d < D_; d++) {
    int idx = j * (D_ + H_) + d;
    float w = (m == 0) ? f1w[idx] : (m == 1) ? f2w[idx] : (0.1f * taw[idx] + tbw[idx]);
    s += w * Cb[d];
  }
  ub[r] = s;
}

// ---------------- LayerNorm -> bf16 ----------------
__global__ __launch_bounds__(256) void k_ln(const float* __restrict__ x,
                                            const float* __restrict__ g,
                                            const float* __restrict__ bta,
                                            unsigned short* __restrict__ xn) {
  int row = blockIdx.x;
  int tid = threadIdx.x;
  const float* xr = x + (size_t)row * D_;
  float4 v = ((const float4*)xr)[tid];
  float s = v.x + v.y + v.z + v.w;
  float q = v.x * v.x + v.y * v.y + v.z * v.z + v.w * v.w;
  for (int off = 32; off >= 1; off >>= 1) {
    s += __shfl_xor(s, off, 64);
    q += __shfl_xor(q, off, 64);
  }
  __shared__ float red[8];
  int wid = tid >> 6, lane = tid & 63;
  if (lane == 0) { red[wid] = s; red[4 + wid] = q; }
  __syncthreads();
  s = red[0] + red[1] + red[2] + red[3];
  q = red[4] + red[5] + red[6] + red[7];
  float mu = s * (1.0f / D_);
  float var = q * (1.0f / D_) - mu * mu;
  float rs = rsqrtf(var + 1e-5f);
  float4 gg = ((const float4*)g)[tid];
  float4 bb = ((const float4*)bta)[tid];
  ushort4 o;
  o.x = f2bf((v.x - mu) * rs * gg.x + bb.x);
  o.y = f2bf((v.y - mu) * rs * gg.y + bb.y);
  o.z = f2bf((v.z - mu) * rs * gg.z + bb.z);
  o.w = f2bf((v.w - mu) * rs * gg.w + bb.w);
  ((ushort4*)(xn + (size_t)row * D_))[tid] = o;
}

// ---------------- generic bf16 MFMA GEMM ----------------
__global__ __launch_bounds__(256) void k_gemm(const unsigned short* __restrict__ A,
                                              const unsigned short* __restrict__ Bm,
                                              const float* __restrict__ bias,
                                              const float* __restrict__ resid,
                                              float* __restrict__ Cf,
                                              unsigned short* __restrict__ Cb,
                                              int M, int N, int K) {
  int nt = N >> 7;
  int bx = blockIdx.x % nt, by = blockIdx.x / nt;
  int m0 = by << 7, n0 = bx << 7;
  int tid = threadIdx.x;
  __shared__ unsigned short Al[4][128][8];
  __shared__ unsigned short Bl[4][128][8];
  int lane = tid & 63, wid = tid >> 6;
  int wr = (wid >> 1) << 6, wc = (wid & 1) << 6;
  f32x4 acc[4][4];
#pragma unroll
  for (int i = 0; i < 4; i++)
#pragma unroll
    for (int j = 0; j < 4; j++) acc[i][j] = (f32x4){0.f, 0.f, 0.f, 0.f};

  int ur0 = tid >> 2, uk = tid & 3;
  int ur1 = ur0 + 64;
  int kt_n = K >> 5;
  for (int kt = 0; kt < kt_n; kt++) {
    int kb = (kt << 5) + (uk << 3);
    uint4 a0 = *(const uint4*)(A + (size_t)(m0 + ur0) * K + kb);
    uint4 a1 = *(const uint4*)(A + (size_t)(m0 + ur1) * K + kb);
    uint4 b0 = *(const uint4*)(Bm + (size_t)(n0 + ur0) * K + kb);
    uint4 b1 = *(const uint4*)(Bm + (size_t)(n0 + ur1) * K + kb);
    *(uint4*)&Al[uk][ur0][0] = a0;
    *(uint4*)&Al[uk][ur1][0] = a1;
    *(uint4*)&Bl[uk][ur0][0] = b0;
    *(uint4*)&Bl[uk][ur1][0] = b1;
    __syncthreads();
    int g = lane >> 4, r = lane & 15;
    bf16x8 af[4], bfv[4];
#pragma unroll
    for (int mf = 0; mf < 4; mf++) af[mf] = *(const bf16x8*)&Al[g][wr + mf * 16 + r][0];
#pragma unroll
    for (int nf = 0; nf < 4; nf++) bfv[nf] = *(const bf16x8*)&Bl[g][wc + nf * 16 + r][0];
#pragma unroll
    for (int mf = 0; mf < 4; mf++)
#pragma unroll
      for (int nf = 0; nf < 4; nf++)
        acc[mf][nf] = __builtin_amdgcn_mfma_f32_16x16x32_bf16(af[mf], bfv[nf], acc[mf][nf], 0, 0, 0);
    __syncthreads();
  }
  int r4 = (lane >> 4) << 2;
  int cl = lane & 15;
#pragma unroll
  for (int mf = 0; mf < 4; mf++) {
#pragma unroll
    for (int nf = 0; nf < 4; nf++) {
#pragma unroll
      for (int e = 0; e < 4; e++) {
        int row = m0 + wr + mf * 16 + r4 + e;
        int col = n0 + wc + nf * 16 + cl;
        float v = acc[mf][nf][e];
        if (bias)  v += bias[col];
        size_t idx = (size_t)row * N + col;
        if (resid) v += resid[idx];
        if (Cb) Cb[idx] = f2bf(v); else Cf[idx] = v;
      }
    }
  }
}

// ---------------- SSM prefix scan ----------------
__global__ __launch_bounds__(1024) void k_ssm(const float* __restrict__ Ball,
                                              const float* __restrict__ A_log,
                                              unsigned short* __restrict__ states,
                                              float* __restrict__ fss) {
  int b = blockIdx.x >> 1, half = blockIdx.x & 1;
  int tid = threadIdx.x;
  int nloc = tid & 63, chunk = tid >> 6;
  int n = half * 64 + nloc;
  float A = 1.0f / (1.0f + expf(-A_log[n]));
  float l2A = log2f(A);
  __shared__ float sums[16][64];
  float acc = 0.f;
  int sbase = chunk << 8;
  for (int i = 0; i < 256; i++) {
    int s = sbase + i;
    float ap = exp2f((float)s * l2A);
    acc += Ball[((size_t)b * S_ + s) * N_ + n] / fmaxf(ap, 1e-8f);
  }
  sums[chunk][nloc] = acc;
  __syncthreads();
  float c = 0.f;
  for (int cc = 0; cc < 16; cc++)
    if (cc < chunk) c += sums[cc][nloc];
  for (int i = 0; i < 256; i++) {
    int s = sbase + i;
    float ap = exp2f((float)s * l2A);
    c += Ball[((size_t)b * S_ + s) * N_ + n] / fmaxf(ap, 1e-8f);
    float st = ap * c;
    states[((size_t)b * S_ + s) * N_ + n] = f2bf(st);
    if (s == S_ - 1) fss[b * N_ + n] = st;
  }
}

// ---------------- CfC sequential scan (v2) ----------------
// 32 persistent blocks (8/batch). h transported as u32 = f16 | tag<<16, 2 parity slots.
// 224 poller lanes each own one remote f16-PAIR (8B, rolling 8-deep poll), strip tags,
// pack f16x2 into LDS. Own 64 h bypass global (act lanes write LDS halfwords).
// Dot: 48 v_dot2_f32_f16 per lane from packed LDS pairs + packed weight regs.
#define AL_(src) __hip_atomic_load((src), __ATOMIC_RELAXED, __HIP_MEMORY_SCOPE_AGENT)
__global__ __launch_bounds__(1024) void k_cfc(const unsigned short* __restrict__ U,
                                              const u32* __restrict__ Whp,
                                              unsigned short* __restrict__ cfc,
                                              float* __restrict__ dout,
                                              u32* __restrict__ hbuf) {
  int bid = blockIdx.x;
  int b = bid >> 3, p = bid & 7;
  int tid = threadIdx.x;
  int jl = tid >> 4, l16 = tid & 15;
  int j = p * 64 + jl;

  // packed f16-pair weights: lane needs Whp[row][l16 + 16*i]
  u32 w1[16], w2[16], w3[16];
  {
    const u32* W1 = Whp + (size_t)j * 256 + l16;
    const u32* W2 = Whp + (size_t)(H_ + j) * 256 + l16;
    const u32* W3 = Whp + (size_t)(2 * H_ + j) * 256 + l16;
#pragma unroll
    for (int i = 0; i < 16; i++) {
      w1[i] = W1[16 * i];
      w2[i] = W2[16 * i];
      w3[i] = W3[16 * i];
    }
  }

  __shared__ u32 lhp[2][256];   // packed f16x2 pairs per parity
  if (l16 == 0) {
    __hip_atomic_store(&hbuf[(size_t)b * 512 + j], 0u, __ATOMIC_RELAXED, __HIP_MEMORY_SCOPE_AGENT);
    ((unsigned short*)&lhp[0][0])[j] = 0;   // own halfword, h0 = 0
  }
  bool poller = (tid < 224);
  int pi = 0;
  if (poller) pi = tid + ((tid >= p * 32) ? 32 : 0);   // skip own 32 pairs

  float hn = 0.f;
  const unsigned short* Ub = U + (size_t)b * S_ * R3_;
  for (int s = 0; s < S_; s++) {
    float u1 = 0.f, u2 = 0.f, u3 = 0.f;
    if (l16 == 0) {
      const unsigned short* up = Ub + (size_t)s * R3_;
      u1 = bf2f(up[j]); u2 = bf2f(up[H_ + j]); u3 = bf2f(up[2 * H_ + j]);
    }
    if (poller) {
      const unsigned long long* src =
        (const unsigned long long*)(hbuf + (size_t)(s & 1) * 2048 + (size_t)b * 512 + 2 * pi);
      u32 want = (u32)(s & 0xFF);
      u32 lo, hi;
      unsigned long long r0 = AL_(src), r1 = AL_(src), r2 = AL_(src), r3 = AL_(src),
                         r4 = AL_(src), r5 = AL_(src), r6 = AL_(src), r7 = AL_(src);
      for (;;) {
#define CHK_(rq) { lo = (u32)rq; hi = (u32)(rq >> 32); \
                   if ((((lo >> 16) & 0xFFu) == want) && (((hi >> 16) & 0xFFu) == want)) break; \
                   rq = AL_(src); }
        CHK_(r0) CHK_(r1) CHK_(r2) CHK_(r3) CHK_(r4) CHK_(r5) CHK_(r6) CHK_(r7)
#undef CHK_
      }
      lhp[s & 1][pi] = (lo & 0xFFFFu) | (hi << 16);
    }
    __syncthreads();

    float z1 = 0.f, z2 = 0.f, z3 = 0.f;
    const u32* lp = &lhp[s & 1][0];
#pragma unroll
    for (int i = 0; i < 16; i++) {
      u32 hw = lp[l16 + 16 * i];
      z1 = dot2f(w1[i], hw, z1);
      z2 = dot2f(w2[i], hw, z2);
      z3 = dot2f(w3[i], hw, z3);
    }
    for (int m = 8; m >= 1; m >>= 1) {
      z1 += __shfl_xor(z1, m, 16);
      z2 += __shfl_xor(z2, m, 16);
      z3 += __shfl_xor(z3, m, 16);
    }
    if (l16 == 0) {
      z1 += u1; z2 += u2; z3 += u3;
      float e1 = __expf(2.f * z1); float a1 = 1.f - 2.f / (e1 + 1.f);
      float e2 = __expf(2.f * z2); float a2 = 1.f - 2.f / (e2 + 1.f);
      float ti = 1.f / (1.f + __expf(-z3));
      hn = a1 + ti * (a2 - a1);
      unsigned short hb = __half_as_ushort(__float2half(hn));
      u32 word = (u32)hb | (((u32)((s + 1) & 0xFF)) << 16);
      __hip_atomic_store(&hbuf[(size_t)((s + 1) & 1) * 2048 + (size_t)b * 512 + j], word,
                         __ATOMIC_RELAXED, __HIP_MEMORY_SCOPE_AGENT);
      ((unsigned short*)&lhp[(s + 1) & 1][0])[j] = hb;   // own halfword for next step
      cfc[((size_t)b * S_ + s) * H_ + j] = f2bf(hn);
    }
  }
  if (l16 == 0) dout[HL_OFF + (size_t)b * H_ + j] = hn;
}

// ---------------- launch ----------------
extern "C" void kernel_launch(void* const* d_in, const int* in_sizes, int n_in,
                              void* d_out, int out_size, void* d_ws, size_t ws_size,
                              hipStream_t stream) {
  const float* x     = (const float*)d_in[0];
  const float* A_log = (const float*)d_in[1];
  const float* B_w   = (const float*)d_in[2];
  const float* B_b   = (const float*)d_in[3];
  const float* C_w   = (const float*)d_in[4];
  const float* C_b   = (const float*)d_in[5];
  const float* ng    = (const float*)d_in[6];
  const float* nbv   = (const float*)d_in[7];
  const float* f1w   = (const float*)d_in[8];
  const float* f1b   = (const float*)d_in[9];
  const float* f2w   = (const float*)d_in[10];
  const float* f2b   = (const float*)d_in[11];
  const float* taw   = (const float*)d_in[12];
  const float* tab   = (const float*)d_in[13];
  const float* tbw   = (const float*)d_in[14];
  const float* tbb   = (const float*)d_in[15];
  const float* ow    = (const float*)d_in[16];
  const float* ob    = (const float*)d_in[17];
  float* dout = (float*)d_out;
  char* ws = (char*)d_ws;

  unsigned short* xn_b     = (unsigned short*)(ws + OFF_XN);
  float*          Ball_f   = (float*)(ws + OFF_BALL);
  unsigned short* U_b      = (unsigned short*)(ws + OFF_U);
  unsigned short* states_b = (unsigned short*)(ws + OFF_STATES);
  unsigned short* cfc_b    = (unsigned short*)(ws + OFF_CFC);
  unsigned short* Bw_b     = (unsigned short*)(ws + OFF_BW);
  unsigned short* CwT_b    = (unsigned short*)(ws + OFF_CWT);
  unsigned short* Wxs_b    = (unsigned short*)(ws + OFF_WXS);
  u32*            Whp_u    = (u32*)(ws + OFF_WHP);
  unsigned short* OW_b     = (unsigned short*)(ws + OFF_OW);
  unsigned short* G_b      = (unsigned short*)(ws + OFF_G);
  float*          ub_f     = (float*)(ws + OFF_UB);
  u32*            hbuf_u   = (u32*)(ws + OFF_HBUF);

  // weight prep
  k_conv<<<(N_ * D_ + 255) / 256, 256, 0, stream>>>(B_w, Bw_b, N_ * D_);
  k_transpose_cw<<<(N_ * D_ + 255) / 256, 256, 0, stream>>>(C_w, CwT_b);
  k_build_wxs<<<(R3_ * D_ + 255) / 256, 256, 0, stream>>>(f1w, f2w, taw, tbw, Wxs_b);
  k_build_whp<<<(R3_ * 256 + 255) / 256, 256, 0, stream>>>(f1w, f2w, taw, tbw, Whp_u);
  k_conv<<<(D_ * H_ + 255) / 256, 256, 0, stream>>>(ow, OW_b, D_ * H_);
  k_build_ub<<<(R3_ + 255) / 256, 256, 0, stream>>>(f1w, f2w, taw, tbw, f1b, f2b, tab, tbb, C_b, ub_f);

  // LN -> xn (bf16)
  k_ln<<<BS_, 256, 0, stream>>>(x, ng, nbv, xn_b);
  // Ball = xn @ B_w^T + B_b   (fp32)
  k_gemm<<<(BS_ / 128) * (N_ / 128), 256, 0, stream>>>(xn_b, Bw_b, B_b, nullptr, Ball_f, nullptr, BS_, N_, 1024);
  // states (bf16) + final_ssm_state -> d_out
  k_ssm<<<8, 1024, 0, stream>>>(Ball_f, A_log, states_b, dout + FSS_OFF);
  // G = Wxs @ C_w  (1536 x 128, bf16)
  k_gemm<<<(R3_ / 128) * (N_ / 128), 256, 0, stream>>>(Wxs_b, CwT_b, nullptr, nullptr, nullptr, G_b, R3_, N_, 1024);
  // U = states @ G^T + ub  (16384 x 1536, bf16)
  k_gemm<<<(BS_ / 128) * (R3_ / 128), 256, 0, stream>>>(states_b, G_b, ub_f, nullptr, nullptr, U_b, BS_, R3_, N_);
  // sequential CfC scan -> cfc (bf16), h_last -> d_out
  k_cfc<<<32, 1024, 0, stream>>>(U_b, Whp_u, cfc_b, dout, hbuf_u);
  // layer_out = x + cfc @ out_w^T + out_b  (fp32 -> d_out)
  k_gemm<<<(BS_ / 128) * (D_ / 128), 256, 0, stream>>>(cfc_b, OW_b, ob, x, dout, nullptr, BS_, D_, H_);

  (void)in_sizes; (void)n_in; (void)out_size; (void)ws_size;
}

// Round 5
// 8994.460 us; speedup vs baseline: 1.3364x; 1.1645x over previous
//
#include <hip/hip_runtime.h>
#include <hip/hip_fp16.h>
#include <stdint.h>

// Problem constants
#define B_  4
#define S_  4096
#define D_  1024
#define N_  128
#define H_  512
#define BS_ (B_ * S_)       // 16384
#define R3_ (3 * H_)        // 1536

typedef unsigned int u32;
typedef short bf16x8 __attribute__((ext_vector_type(8)));
typedef float f32x4  __attribute__((ext_vector_type(4)));
typedef _Float16 f16x2 __attribute__((ext_vector_type(2)));

// d_out layout: layer_out [BS_*D_] | final_ssm_state [B_*N_] | h_last [B_*H_]
#define FSS_OFF ((size_t)BS_ * D_)          // 16777216
#define HL_OFF  (FSS_OFF + (size_t)B_ * N_) // 16777728

// Workspace layout (bytes). U overlays xn+Ball (dead by the time U is written).
#define OFF_XN     ((size_t)0)
#define OFF_BALL   ((size_t)33554432)
#define OFF_U      ((size_t)0)
#define OFF_STATES ((size_t)50331648)
#define OFF_CFC    ((size_t)54525952)
#define OFF_BW     ((size_t)71303168)
#define OFF_CWT    ((size_t)71565312)
#define OFF_WXS    ((size_t)71827456)
#define OFF_WHP    ((size_t)74973184)   // f16-pair weights [1536][256] u32 = 1.5 MB
#define OFF_OW     ((size_t)76546048)
#define OFF_G      ((size_t)77594624)
#define OFF_UB     ((size_t)77987840)
#define OFF_HBUF   ((size_t)77993984)   // 2 slots * 4 * 512 u32 = 16 KiB

__device__ __forceinline__ unsigned short f2bf(float f) {
  u32 u = __float_as_uint(f);
  u32 r = (u + 0x7FFFu + ((u >> 16) & 1u)) >> 16;
  return (unsigned short)r;
}
__device__ __forceinline__ float bf2f(unsigned short h) {
  return __uint_as_float(((u32)h) << 16);
}

// dot2: f16x2 * f16x2 + f32, with fallback if the builtin is unavailable
__device__ __forceinline__ float dot2f(u32 wa, u32 hb, float acc) {
#if __has_builtin(__builtin_amdgcn_fdot2)
  return __builtin_amdgcn_fdot2(__builtin_bit_cast(f16x2, wa),
                                __builtin_bit_cast(f16x2, hb), acc, false);
#else
  f16x2 a = __builtin_bit_cast(f16x2, wa);
  f16x2 b = __builtin_bit_cast(f16x2, hb);
  return acc + (float)a[0] * (float)b[0] + (float)a[1] * (float)b[1];
#endif
}

__device__ __forceinline__ float rcp_(float x) {
#if __has_builtin(__builtin_amdgcn_rcpf)
  return __builtin_amdgcn_rcpf(x);
#else
  return 1.f / x;
#endif
}
__device__ __forceinline__ float exp2_(float x) {
#if __has_builtin(__builtin_amdgcn_exp2f)
  return __builtin_amdgcn_exp2f(x);
#else
  return exp2f(x);
#endif
}

// 16-lane rotate-allreduce: pure VALU via DPP row_ror (no DS-pipe traffic)
#if __has_builtin(__builtin_amdgcn_mov_dpp)
#define DPPADD_(z, CTRL) { int t_ = __builtin_amdgcn_mov_dpp(__float_as_int(z), CTRL, 0xF, 0xF, false); z += __int_as_float(t_); }
#define REDUCE16(z) { DPPADD_(z, 0x121) DPPADD_(z, 0x122) DPPADD_(z, 0x124) DPPADD_(z, 0x128) }
#else
#define REDUCE16(z) { z += __shfl_xor(z, 1, 16); z += __shfl_xor(z, 2, 16); z += __shfl_xor(z, 4, 16); z += __shfl_xor(z, 8, 16); }
#endif

// ---------------- weight prep ----------------
__global__ void k_conv(const float* __restrict__ src, unsigned short* __restrict__ dst, int n) {
  int i = blockIdx.x * 256 + threadIdx.x;
  if (i < n) dst[i] = f2bf(src[i]);
}

__global__ void k_transpose_cw(const float* __restrict__ Cw, unsigned short* __restrict__ CwT) {
  int i = blockIdx.x * 256 + threadIdx.x;   // over N_*D_
  if (i < N_ * D_) {
    int n = i >> 10, d = i & 1023;
    CwT[i] = f2bf(Cw[d * N_ + n]);
  }
}

__global__ void k_build_wxs(const float* __restrict__ f1, const float* __restrict__ f2,
                            const float* __restrict__ ta, const float* __restrict__ tb,
                            unsigned short* __restrict__ Wxs) {
  int i = blockIdx.x * 256 + threadIdx.x;   // over R3_*D_
  if (i >= R3_ * D_) return;
  int r = i >> 10, d = i & 1023;
  int m = r >> 9, j = r & 511;
  int idx = j * (D_ + H_) + d;
  float v = (m == 0) ? f1[idx] : (m == 1) ? f2[idx] : (0.1f * ta[idx] + tb[idx]);
  Wxs[i] = f2bf(v);
}

// h-part weights as f16 PAIRS: Whp[row][pi] = f16(W[row][2pi]) | f16(W[row][2pi+1])<<16
__global__ void k_build_whp(const float* __restrict__ f1, const float* __restrict__ f2,
                            const float* __restrict__ ta, const float* __restrict__ tb,
                            u32* __restrict__ Whp) {
  int i = blockIdx.x * 256 + threadIdx.x;   // over R3_*256
  if (i >= R3_ * 256) return;
  int r = i >> 8, pi = i & 255;
  int m = r >> 9, j = r & 511;
  int idx0 = j * (D_ + H_) + D_ + 2 * pi;
  float v0 = (m == 0) ? f1[idx0] : (m == 1) ? f2[idx0] : (0.1f * ta[idx0] + tb[idx0]);
  float v1 = (m == 0) ? f1[idx0+1] : (m == 1) ? f2[idx0+1] : (0.1f * ta[idx0+1] + tb[idx0+1]);
  u32 lo = __half_as_ushort(__float2half(v0));
  u32 hi = __half_as_ushort(__float2half(v1));
  Whp[i] = lo | (hi << 16);
}

// ub[r] = sum_d Wx[r][d]*C_b[d] + bias_r   (folds C_b through the x-part)
__global__ void k_build_ub(const float* __restrict__ f1w, const float* __restrict__ f2w,
                           const float* __restrict__ taw, const float* __restrict__ tbw,
                           const float* __restrict__ f1b, const float* __restrict__ f2b,
                           const float* __restrict__ tab, const float* __restrict__ tbb,
                           const float* __restrict__ Cb, float* __restrict__ ub) {
  int r = blockIdx.x * 256 + threadIdx.x;
  if (r >= R3_) return;
  int m = r >> 9, j = r & 511;
  float s = (m == 0) ? f1b[j] : (m == 1) ? f2b[j] : (0.1f * tab[j] + tbb[j]);
  for (int d = 0; d < D_; d++) {
    int idx = j * (D_ + H_) + d;
    float w = (m == 0) ? f1w[idx] : (m == 1) ? f2w[idx] : (0.1f * taw[idx] + tbw[idx]);
    s += w * Cb[d];
  }
  ub[r] = s;
}

// ---------------- LayerNorm -> bf16 ----------------
__global__ __launch_bounds__(256) void k_ln(const float* __restrict__ x,
                                            const float* __restrict__ g,
                                            const float* __restrict__ bta,
                                            unsigned short* __restrict__ xn) {
  int row = blockIdx.x;
  int tid = threadIdx.x;
  const float* xr = x + (size_t)row * D_;
  float4 v = ((const float4*)xr)[tid];
  float s = v.x + v.y + v.z + v.w;
  float q = v.x * v.x + v.y * v.y + v.z * v.z + v.w * v.w;
  for (int off = 32; off >= 1; off >>= 1) {
    s += __shfl_xor(s, off, 64);
    q += __shfl_xor(q, off, 64);
  }
  __shared__ float red[8];
  int wid = tid >> 6, lane = tid & 63;
  if (lane == 0) { red[wid] = s; red[4 + wid] = q; }
  __syncthreads();
  s = red[0] + red[1] + red[2] + red[3];
  q = red[4] + red[5] + red[6] + red[7];
  float mu = s * (1.0f / D_);
  float var = q * (1.0f / D_) - mu * mu;
  float rs = rsqrtf(var + 1e-5f);
  float4 gg = ((const float4*)g)[tid];
  float4 bb = ((const float4*)bta)[tid];
  ushort4 o;
  o.x = f2bf((v.x - mu) * rs * gg.x + bb.x);
  o.y = f2bf((v.y - mu) * rs * gg.y + bb.y);
  o.z = f2bf((v.z - mu) * rs * gg.z + bb.z);
  o.w = f2bf((v.w - mu) * rs * gg.w + bb.w);
  ((ushort4*)(xn + (size_t)row * D_))[tid] = o;
}

// ---------------- generic bf16 MFMA GEMM ----------------
__global__ __launch_bounds__(256) void k_gemm(const unsigned short* __restrict__ A,
                                              const unsigned short* __restrict__ Bm,
                                              const float* __restrict__ bias,
                                              const float* __restrict__ resid,
                                              float* __restrict__ Cf,
                                              unsigned short* __restrict__ Cb,
                                              int M, int N, int K) {
  int nt = N >> 7;
  int bx = blockIdx.x % nt, by = blockIdx.x / nt;
  int m0 = by << 7, n0 = bx << 7;
  int tid = threadIdx.x;
  __shared__ unsigned short Al[4][128][8];
  __shared__ unsigned short Bl[4][128][8];
  int lane = tid & 63, wid = tid >> 6;
  int wr = (wid >> 1) << 6, wc = (wid & 1) << 6;
  f32x4 acc[4][4];
#pragma unroll
  for (int i = 0; i < 4; i++)
#pragma unroll
    for (int j = 0; j < 4; j++) acc[i][j] = (f32x4){0.f, 0.f, 0.f, 0.f};

  int ur0 = tid >> 2, uk = tid & 3;
  int ur1 = ur0 + 64;
  int kt_n = K >> 5;
  for (int kt = 0; kt < kt_n; kt++) {
    int kb = (kt << 5) + (uk << 3);
    uint4 a0 = *(const uint4*)(A + (size_t)(m0 + ur0) * K + kb);
    uint4 a1 = *(const uint4*)(A + (size_t)(m0 + ur1) * K + kb);
    uint4 b0 = *(const uint4*)(Bm + (size_t)(n0 + ur0) * K + kb);
    uint4 b1 = *(const uint4*)(Bm + (size_t)(n0 + ur1) * K + kb);
    *(uint4*)&Al[uk][ur0][0] = a0;
    *(uint4*)&Al[uk][ur1][0] = a1;
    *(uint4*)&Bl[uk][ur0][0] = b0;
    *(uint4*)&Bl[uk][ur1][0] = b1;
    __syncthreads();
    int g = lane >> 4, r = lane & 15;
    bf16x8 af[4], bfv[4];
#pragma unroll
    for (int mf = 0; mf < 4; mf++) af[mf] = *(const bf16x8*)&Al[g][wr + mf * 16 + r][0];
#pragma unroll
    for (int nf = 0; nf < 4; nf++) bfv[nf] = *(const bf16x8*)&Bl[g][wc + nf * 16 + r][0];
#pragma unroll
    for (int mf = 0; mf < 4; mf++)
#pragma unroll
      for (int nf = 0; nf < 4; nf++)
        acc[mf][nf] = __builtin_amdgcn_mfma_f32_16x16x32_bf16(af[mf], bfv[nf], acc[mf][nf], 0, 0, 0);
    __syncthreads();
  }
  int r4 = (lane >> 4) << 2;
  int cl = lane & 15;
#pragma unroll
  for (int mf = 0; mf < 4; mf++) {
#pragma unroll
    for (int nf = 0; nf < 4; nf++) {
#pragma unroll
      for (int e = 0; e < 4; e++) {
        int row = m0 + wr + mf * 16 + r4 + e;
        int col = n0 + wc + nf * 16 + cl;
        float v = acc[mf][nf][e];
        if (bias)  v += bias[col];
        size_t idx = (size_t)row * N + col;
        if (resid) v += resid[idx];
        if (Cb) Cb[idx] = f2bf(v); else Cf[idx] = v;
      }
    }
  }
}

// ---------------- SSM prefix scan ----------------
__global__ __launch_bounds__(1024) void k_ssm(const float* __restrict__ Ball,
                                              const float* __restrict__ A_log,
                                              unsigned short* __restrict__ states,
                                              float* __restrict__ fss) {
  int b = blockIdx.x >> 1, half = blockIdx.x & 1;
  int tid = threadIdx.x;
  int nloc = tid & 63, chunk = tid >> 6;
  int n = half * 64 + nloc;
  float A = 1.0f / (1.0f + expf(-A_log[n]));
  float l2A = log2f(A);
  __shared__ float sums[16][64];
  float acc = 0.f;
  int sbase = chunk << 8;
  for (int i = 0; i < 256; i++) {
    int s = sbase + i;
    float ap = exp2f((float)s * l2A);
    acc += Ball[((size_t)b * S_ + s) * N_ + n] / fmaxf(ap, 1e-8f);
  }
  sums[chunk][nloc] = acc;
  __syncthreads();
  float c = 0.f;
  for (int cc = 0; cc < 16; cc++)
    if (cc < chunk) c += sums[cc][nloc];
  for (int i = 0; i < 256; i++) {
    int s = sbase + i;
    float ap = exp2f((float)s * l2A);
    c += Ball[((size_t)b * S_ + s) * N_ + n] / fmaxf(ap, 1e-8f);
    float st = ap * c;
    states[((size_t)b * S_ + s) * N_ + n] = f2bf(st);
    if (s == S_ - 1) fss[b * N_ + n] = st;
  }
}

// ---------------- CfC sequential scan (v3: barrier-free) ----------------
// 32 persistent blocks (8/batch), 768 threads: 512 compute (32 groups x16, 2 j each),
// 224 pollers (persistent 8-deep rolling polls, never drained), rest idle.
// Sync via monotonic LDS counters (cnt: pairs ready per parity slot; rdone: wave
// read-completion per slot). No __syncthreads in the loop -> no vmcnt drains.
// h transport: u32 = f16 | tag<<16 in global hbuf, 2 parity slots, self-validating tags.
// LDS h storage transposed+padded [16][18] -> conflict-free ds_read_b64.
// Reduce: DPP row_ror rotate-allreduce (VALU). Act: exp2/rcp fast path.
#define AL_(src) __hip_atomic_load((src), __ATOMIC_RELAXED, __HIP_MEMORY_SCOPE_AGENT)
#define LDSFENCE_ asm volatile("s_waitcnt lgkmcnt(0)" ::: "memory")
__global__ __launch_bounds__(768) void k_cfc(const unsigned short* __restrict__ U,
                                             const u32* __restrict__ Whp,
                                             unsigned short* __restrict__ cfc,
                                             float* __restrict__ dout,
                                             u32* __restrict__ hbuf) {
  int bid = blockIdx.x;
  int b = bid >> 3, p = bid & 7;
  int tid = threadIdx.x;

  __shared__ u32 lhpT[2][16][18];   // pair pg at [pg&15][pg>>4], rows padded to 18
  __shared__ u32 cnt[2];            // pairs ready per parity slot (monotonic)
  __shared__ u32 rdone[2];          // compute-wave read completions per slot (monotonic)

  if (tid == 0) { cnt[0] = 64u; cnt[1] = 0u; rdone[0] = 0u; rdone[1] = 0u; }  // pre-credit own 32 pairs
  if (tid < 32) { int pg = p * 32 + tid; lhpT[0][pg & 15][pg >> 4] = 0u; }    // h0 = 0
  if (tid < 64) {
    __hip_atomic_store(&hbuf[(size_t)b * 512 + p * 64 + tid], 0u,
                       __ATOMIC_RELAXED, __HIP_MEMORY_SCOPE_AGENT);           // tag 0
  }
  __syncthreads();   // only barrier in the kernel

  if (tid < 512) {
    // ---------------- compute lanes ----------------
    int l16 = tid & 15, g = tid >> 4;            // group g owns j = 2g, 2g+1 (block-local)
    int jA = p * 64 + 2 * g, jB = jA + 1;
    u32 wA1[16], wA2[16], wA3[16], wB1[16], wB2[16], wB3[16];
    {
      const u32* A1 = Whp + (size_t)jA * 256 + l16;
      const u32* A2 = Whp + (size_t)(H_ + jA) * 256 + l16;
      const u32* A3 = Whp + (size_t)(2 * H_ + jA) * 256 + l16;
      const u32* B1 = Whp + (size_t)jB * 256 + l16;
      const u32* B2 = Whp + (size_t)(H_ + jB) * 256 + l16;
      const u32* B3 = Whp + (size_t)(2 * H_ + jB) * 256 + l16;
#pragma unroll
      for (int i = 0; i < 16; i++) {
        wA1[i] = A1[16 * i]; wA2[i] = A2[16 * i]; wA3[i] = A3[16 * i];
        wB1[i] = B1[16 * i]; wB2[i] = B2[16 * i]; wB3[i] = B3[16 * i];
      }
    }
    int jj = jA + (l16 & 1);                     // act lane's j (valid for l16<2)
    int pgown = p * 32 + g;
    float hn = 0.f;
    const unsigned short* Ub = U + (size_t)b * S_ * R3_;
    for (int s = 0; s < S_; s++) {
      int par = s & 1;
      u32 target = 288u * ((u32)(s >> 1) + 1u);
      float u1 = 0.f, u2 = 0.f, u3 = 0.f;
      if (l16 < 2) {                             // issue early, consumed after reduce
        const unsigned short* up = Ub + (size_t)s * R3_;
        u1 = bf2f(up[jj]); u2 = bf2f(up[H_ + jj]); u3 = bf2f(up[2 * H_ + jj]);
      }
      while (__hip_atomic_load(&cnt[par], __ATOMIC_RELAXED, __HIP_MEMORY_SCOPE_WORKGROUP) < target) {}
      LDSFENCE_;
      float zA1 = 0.f, zA2 = 0.f, zA3 = 0.f, zB1 = 0.f, zB2 = 0.f, zB3 = 0.f;
      const uint2* row = (const uint2*)&lhpT[par][l16][0];
#pragma unroll
      for (int i2 = 0; i2 < 8; i2++) {
        uint2 hw = row[i2];
        zA1 = dot2f(wA1[2 * i2], hw.x, zA1); zA1 = dot2f(wA1[2 * i2 + 1], hw.y, zA1);
        zA2 = dot2f(wA2[2 * i2], hw.x, zA2); zA2 = dot2f(wA2[2 * i2 + 1], hw.y, zA2);
        zA3 = dot2f(wA3[2 * i2], hw.x, zA3); zA3 = dot2f(wA3[2 * i2 + 1], hw.y, zA3);
        zB1 = dot2f(wB1[2 * i2], hw.x, zB1); zB1 = dot2f(wB1[2 * i2 + 1], hw.y, zB1);
        zB2 = dot2f(wB2[2 * i2], hw.x, zB2); zB2 = dot2f(wB2[2 * i2 + 1], hw.y, zB2);
        zB3 = dot2f(wB3[2 * i2], hw.x, zB3); zB3 = dot2f(wB3[2 * i2 + 1], hw.y, zB3);
      }
      REDUCE16(zA1); REDUCE16(zA2); REDUCE16(zA3);
      REDUCE16(zB1); REDUCE16(zB2); REDUCE16(zB3);
      LDSFENCE_;                                 // reads complete before rdone signal
      if ((tid & 63) == 0)
        __hip_atomic_fetch_add(&rdone[par], 1u, __ATOMIC_RELAXED, __HIP_MEMORY_SCOPE_WORKGROUP);
      float s1 = (l16 == 0) ? zA1 : zB1;
      float s2 = (l16 == 0) ? zA2 : zB2;
      float s3 = (l16 == 0) ? zA3 : zB3;
      if (l16 < 2) {
        s1 += u1; s2 += u2; s3 += u3;
        float a1 = 1.f - 2.f * rcp_(exp2_(s1 * 2.8853900817779268f) + 1.f);
        float a2 = 1.f - 2.f * rcp_(exp2_(s2 * 2.8853900817779268f) + 1.f);
        float ti = rcp_(1.f + exp2_(-s3 * 1.4426950408889634f));
        float h2 = a1 + ti * (a2 - a1);
        hn = h2;
        unsigned short hb16 = __half_as_ushort(__float2half(h2));
        u32 word = (u32)hb16 | (((u32)((s + 1) & 0xFF)) << 16);
        __hip_atomic_store(&hbuf[(size_t)((s + 1) & 1) * 2048 + (size_t)b * 512 + jj], word,
                           __ATOMIC_RELAXED, __HIP_MEMORY_SCOPE_AGENT);
        ((unsigned short*)&lhpT[(s + 1) & 1][pgown & 15][pgown >> 4])[l16] = hb16;
        LDSFENCE_;
        __hip_atomic_fetch_add(&cnt[(s + 1) & 1], 1u, __ATOMIC_RELAXED, __HIP_MEMORY_SCOPE_WORKGROUP);
        cfc[((size_t)b * S_ + s) * H_ + jj] = f2bf(h2);
      }
    }
    if (l16 < 2) dout[HL_OFF + (size_t)b * H_ + jj] = hn;
  } else if (tid < 736) {
    // ---------------- poller lanes (persistent rolling polls) ----------------
    int idx = tid - 512;
    int pi = idx + ((idx >= p * 32) ? 32 : 0);   // skip own 32 pairs
    const unsigned long long* src =
      (const unsigned long long*)(hbuf + (size_t)b * 512 + 2 * pi);
    unsigned long long r0 = AL_(src), r1 = AL_(src), r2 = AL_(src), r3 = AL_(src),
                       r4 = AL_(src), r5 = AL_(src), r6 = AL_(src), r7 = AL_(src);
    for (int s = 0; s < S_; s++) {
      int par = s & 1;
      src = (const unsigned long long*)(hbuf + (size_t)par * 2048 + (size_t)b * 512 + 2 * pi);
      u32 want = (u32)(s & 0xFF);
      u32 lo, hi;
      for (;;) {
#define CHK_(rq) { lo = (u32)rq; hi = (u32)(rq >> 32); \
                   if ((((lo >> 16) & 0xFFu) == want) && (((hi >> 16) & 0xFFu) == want)) break; \
                   rq = AL_(src); }
        CHK_(r0) CHK_(r1) CHK_(r2) CHK_(r3) CHK_(r4) CHK_(r5) CHK_(r6) CHK_(r7)
#undef CHK_
      }
      if (s >= 2) {                              // gate: step s-2 readers of this slot done
        u32 tgt = 8u * (u32)(s >> 1);
        while (__hip_atomic_load(&rdone[par], __ATOMIC_RELAXED, __HIP_MEMORY_SCOPE_WORKGROUP) < tgt) {}
        LDSFENCE_;
      }
      lhpT[par][pi & 15][pi >> 4] = (lo & 0xFFFFu) | (hi << 16);
      LDSFENCE_;
      __hip_atomic_fetch_add(&cnt[par], 1u, __ATOMIC_RELAXED, __HIP_MEMORY_SCOPE_WORKGROUP);
    }
  }
  // lanes 736..767: idle, exit
}

// ---------------- launch ----------------
extern "C" void kernel_launch(void* const* d_in, const int* in_sizes, int n_in,
                              void* d_out, int out_size, void* d_ws, size_t ws_size,
                              hipStream_t stream) {
  const float* x     = (const float*)d_in[0];
  const float* A_log = (const float*)d_in[1];
  const float* B_w   = (const float*)d_in[2];
  const float* B_b   = (const float*)d_in[3];
  const float* C_w   = (const float*)d_in[4];
  const float* C_b   = (const float*)d_in[5];
  const float* ng    = (const float*)d_in[6];
  const float* nbv   = (const float*)d_in[7];
  const float* f1w   = (const float*)d_in[8];
  const float* f1b   = (const float*)d_in[9];
  const float* f2w   = (const float*)d_in[10];
  const float* f2b   = (const float*)d_in[11];
  const float* taw   = (const float*)d_in[12];
  const float* tab   = (const float*)d_in[13];
  const float* tbw   = (const float*)d_in[14];
  const float* tbb   = (const float*)d_in[15];
  const float* ow    = (const float*)d_in[16];
  const float* ob    = (const float*)d_in[17];
  float* dout = (float*)d_out;
  char* ws = (char*)d_ws;

  unsigned short* xn_b     = (unsigned short*)(ws + OFF_XN);
  float*          Ball_f   = (float*)(ws + OFF_BALL);
  unsigned short* U_b      = (unsigned short*)(ws + OFF_U);
  unsigned short* states_b = (unsigned short*)(ws + OFF_STATES);
  unsigned short* cfc_b    = (unsigned short*)(ws + OFF_CFC);
  unsigned short* Bw_b     = (unsigned short*)(ws + OFF_BW);
  unsigned short* CwT_b    = (unsigned short*)(ws + OFF_CWT);
  unsigned short* Wxs_b    = (unsigned short*)(ws + OFF_WXS);
  u32*            Whp_u    = (u32*)(ws + OFF_WHP);
  unsigned short* OW_b     = (unsigned short*)(ws + OFF_OW);
  unsigned short* G_b      = (unsigned short*)(ws + OFF_G);
  float*          ub_f     = (float*)(ws + OFF_UB);
  u32*            hbuf_u   = (u32*)(ws + OFF_HBUF);

  // weight prep
  k_conv<<<(N_ * D_ + 255) / 256, 256, 0, stream>>>(B_w, Bw_b, N_ * D_);
  k_transpose_cw<<<(N_ * D_ + 255) / 256, 256, 0, stream>>>(C_w, CwT_b);
  k_build_wxs<<<(R3_ * D_ + 255) / 256, 256, 0, stream>>>(f1w, f2w, taw, tbw, Wxs_b);
  k_build_whp<<<(R3_ * 256 + 255) / 256, 256, 0, stream>>>(f1w, f2w, taw, tbw, Whp_u);
  k_conv<<<(D_ * H_ + 255) / 256, 256, 0, stream>>>(ow, OW_b, D_ * H_);
  k_build_ub<<<(R3_ + 255) / 256, 256, 0, stream>>>(f1w, f2w, taw, tbw, f1b, f2b, tab, tbb, C_b, ub_f);

  // LN -> xn (bf16)
  k_ln<<<BS_, 256, 0, stream>>>(x, ng, nbv, xn_b);
  // Ball = xn @ B_w^T + B_b   (fp32)
  k_gemm<<<(BS_ / 128) * (N_ / 128), 256, 0, stream>>>(xn_b, Bw_b, B_b, nullptr, Ball_f, nullptr, BS_, N_, 1024);
  // states (bf16) + final_ssm_state -> d_out
  k_ssm<<<8, 1024, 0, stream>>>(Ball_f, A_log, states_b, dout + FSS_OFF);
  // G = Wxs @ C_w  (1536 x 128, bf16)
  k_gemm<<<(R3_ / 128) * (N_ / 128), 256, 0, stream>>>(Wxs_b, CwT_b, nullptr, nullptr, nullptr, G_b, R3_, N_, 1024);
  // U = states @ G^T + ub  (16384 x 1536, bf16)
  k_gemm<<<(BS_ / 128) * (R3_ / 128), 256, 0, stream>>>(states_b, G_b, ub_f, nullptr, nullptr, U_b, BS_, R3_, N_);
  // sequential CfC scan -> cfc (bf16), h_last -> d_out
  k_cfc<<<32, 768, 0, stream>>>(U_b, Whp_u, cfc_b, dout, hbuf_u);
  // layer_out = x + cfc @ out_w^T + out_b  (fp32 -> d_out)
  k_gemm<<<(BS_ / 128) * (D_ / 128), 256, 0, stream>>>(cfc_b, OW_b, ob, x, dout, nullptr, BS_, D_, H_);

  (void)in_sizes; (void)n_in; (void)out_size; (void)ws_size;
}